// Round 5
// baseline (1266.955 us; speedup 1.0000x reference)
//
#include <hip/hip_runtime.h>
#include <math.h>

#define NEG 0.2f

// -------- dtype hedge: detect int64-vs-int32 index buffers, normalize to int32 ----
// Interpreted as int32, an int64 array of small nonneg values has all odd words == 0.
// Genuine int32 src[] (random node ids) has ~all odd words nonzero.
__global__ void k_detect(const int* __restrict__ ei32, int* __restrict__ flag) {
    if (threadIdx.x == 0) {
        int any = 0;
        for (int i = 0; i < 128; ++i) any |= ei32[2 * i + 1];
        *flag = (any == 0) ? 1 : 0;  // 1 => buffers are int64
    }
}

__global__ void k_cvt(const void* __restrict__ buf, int* __restrict__ out, int n,
                      const int* __restrict__ flag) {
    int i = blockIdx.x * 256 + threadIdx.x;
    if (i >= n) return;
    if (*flag) out[i] = (int)((const long long*)buf)[i];
    else       out[i] = ((const int*)buf)[i];
}

// -------- K0: v1 = We1 @ att_edge1 [384], v2 = We2 @ att_edge2 [384] --------
__global__ void k_vedge(const float* __restrict__ We1, const float* __restrict__ ae1,
                        const float* __restrict__ We2, const float* __restrict__ ae2,
                        float* __restrict__ v1, float* __restrict__ v2) {
    int t = threadIdx.x;
    if (t < 384) {
        float a = 0.f;
        for (int j = 0; j < 32; ++j) a += We1[t * 32 + j] * ae1[j];
        v1[t] = a;
        float b = 0.f;
        for (int j = 0; j < 128; ++j) b += We2[t * 128 + j] * ae2[j];
        v2[t] = b;
    }
}

// -------- K1: a_edge{1,2}[e] = dot(edge_attr[e,:], v{1,2})  (768 MB read) --------
__global__ __launch_bounds__(256) void k_aedge(const float* __restrict__ ea,
                                               const float* __restrict__ v1,
                                               const float* __restrict__ v2,
                                               float* __restrict__ o1,
                                               float* __restrict__ o2, int E) {
    __shared__ float4 v1s[96], v2s[96];
    int tid = threadIdx.x;
    if (tid < 96) {
        v1s[tid] = ((const float4*)v1)[tid];
        v2s[tid] = ((const float4*)v2)[tid];
    }
    __syncthreads();
    int e = blockIdx.x * 8 + (tid >> 5);
    int gl = tid & 31;
    if (e >= E) return;
    const float4* p = (const float4*)ea + (size_t)e * 96;
    float a1 = 0.f, a2 = 0.f;
#pragma unroll
    for (int j = 0; j < 3; ++j) {
        int idx = j * 32 + gl;
        float4 x = p[idx];
        float4 w = v1s[idx];
        a1 += x.x * w.x + x.y * w.y + x.z * w.z + x.w * w.w;
        w = v2s[idx];
        a2 += x.x * w.x + x.y * w.y + x.z * w.z + x.w * w.w;
    }
#pragma unroll
    for (int off = 16; off >= 1; off >>= 1) {
        a1 += __shfl_xor(a1, off);
        a2 += __shfl_xor(a2, off);
    }
    if (gl == 0) { o1[e] = a1; o2[e] = a2; }
}

// -------- K2: hs1 = emb[x] @ W1 [N,32]; a_src1, a_dst1 --------
__global__ __launch_bounds__(256) void k_node1(const int* __restrict__ x,
                                               const float* __restrict__ emb,
                                               const float* __restrict__ W,
                                               const float* __restrict__ att_s,
                                               const float* __restrict__ att_d,
                                               float* __restrict__ hs,
                                               float* __restrict__ asrc,
                                               float* __restrict__ adst, int N) {
    __shared__ float Ws[128 * 32];
    __shared__ float hrow[8][128];
    int tid = threadIdx.x;
    for (int i = tid; i < 4096; i += 256) Ws[i] = W[i];
    int n0 = blockIdx.x * 8;
    for (int i = tid; i < 8 * 128; i += 256) {
        int nl = i >> 7, k = i & 127;
        int g = n0 + nl;
        hrow[nl][k] = (g < N) ? emb[(size_t)x[g] * 128 + k] : 0.f;
    }
    __syncthreads();
    int nl = tid >> 5, j = tid & 31;
    int node = n0 + nl;
    if (node >= N) return;
    float acc = 0.f;
#pragma unroll 8
    for (int k = 0; k < 128; ++k) acc += hrow[nl][k] * Ws[k * 32 + j];
    hs[(size_t)node * 32 + j] = acc;
    float as = acc * att_s[j], ad = acc * att_d[j];
#pragma unroll
    for (int off = 16; off >= 1; off >>= 1) {
        as += __shfl_xor(as, off);
        ad += __shfl_xor(ad, off);
    }
    if (j == 0) { asrc[node] = as; adst[node] = ad; }
}

// -------- CSR build --------
__global__ void k_count(const int* __restrict__ dst, int* __restrict__ cnt, int E) {
    int e = blockIdx.x * 256 + threadIdx.x;
    if (e < E) atomicAdd(&cnt[dst[e]], 1);
}

__global__ void k_scan1(const int* __restrict__ cnt, int* __restrict__ ro,
                        int* __restrict__ csum, int N) {
    __shared__ int s[256];
    int t = threadIdx.x;
    int i = blockIdx.x * 256 + t;
    int v = (i < N) ? cnt[i] : 0;
    s[t] = v;
    __syncthreads();
    for (int off = 1; off < 256; off <<= 1) {
        int xv = (t >= off) ? s[t - off] : 0;
        __syncthreads();
        s[t] += xv;
        __syncthreads();
    }
    if (i < N) ro[i + 1] = s[t];
    if (t == 255) csum[blockIdx.x] = s[255];
}

__global__ void k_scan2(int* __restrict__ csum, int nch) {
    __shared__ int s[256];
    int t = threadIdx.x;
    int v = (t < nch) ? csum[t] : 0;
    s[t] = v;
    __syncthreads();
    for (int off = 1; off < 256; off <<= 1) {
        int xv = (t >= off) ? s[t - off] : 0;
        __syncthreads();
        s[t] += xv;
        __syncthreads();
    }
    if (t < nch) csum[t] = s[t] - v;  // exclusive chunk offsets
}

__global__ void k_scan3(int* __restrict__ ro, int* __restrict__ cur,
                        const int* __restrict__ csum, int N) {
    int i = blockIdx.x * 256 + threadIdx.x;
    if (i == 0) { ro[0] = 0; cur[0] = 0; }
    if (i < N) {
        int v = ro[i + 1] + csum[i >> 8];
        ro[i + 1] = v;
        cur[i + 1] = v;
    }
}

__global__ void k_fill(const int* __restrict__ srcA, const int* __restrict__ dstA,
                       const float* __restrict__ ae1, const float* __restrict__ ae2,
                       int* __restrict__ cur, int* __restrict__ srcs,
                       float* __restrict__ ae1s, float* __restrict__ ae2s, int E) {
    int e = blockIdx.x * 256 + threadIdx.x;
    if (e >= E) return;
    int d = dstA[e];
    int p = atomicAdd(&cur[d], 1);
    srcs[p] = srcA[e];
    ae1s[p] = ae1[e];
    ae2s[p] = ae2[e];
}

// -------- K5: layer-1 softmax + aggregation (C=32, 16 lanes/node) --------
__global__ __launch_bounds__(256) void k_agg1(const int* __restrict__ ro,
                                              const int* __restrict__ srcs,
                                              const float* __restrict__ ae1s,
                                              const float* __restrict__ asrc,
                                              const float* __restrict__ adst,
                                              const float* __restrict__ hs,
                                              float* __restrict__ out, int N) {
    int tid = threadIdx.x;
    int node = blockIdx.x * 16 + (tid >> 4);
    int gl = tid & 15;
    if (node >= N) return;
    int base = ro[node], end = ro[node + 1];
    float ad = adst[node];
    float m = -3.4e38f;
    for (int p = base + gl; p < end; p += 16) {
        int s = srcs[p];
        float al = asrc[s] + ad + ae1s[p];
        al = (al >= 0.f) ? al : NEG * al;
        m = fmaxf(m, al);
    }
#pragma unroll
    for (int off = 8; off >= 1; off >>= 1) m = fmaxf(m, __shfl_xor(m, off));
    float acc0 = 0.f, acc1 = 0.f, ss = 0.f;
    const float2* hp = (const float2*)hs;
    for (int p = base; p < end; ++p) {
        int s = srcs[p];
        float al = asrc[s] + ad + ae1s[p];
        al = (al >= 0.f) ? al : NEG * al;
        float w = __expf(al - m);
        ss += w;
        float2 hv = hp[(size_t)s * 16 + gl];
        acc0 += w * hv.x;
        acc1 += w * hv.y;
    }
    float inv = 1.f / (ss + 1e-16f);
    out[(size_t)node * 32 + gl * 2] = acc0 * inv;
    out[(size_t)node * 32 + gl * 2 + 1] = acc1 * inv;
}

// -------- K6: t = relu(out1 + b1); hs2 = t @ W2 [N,128]; a_src2, a_dst2 --------
__global__ __launch_bounds__(256) void k_node2(const float* __restrict__ out1,
                                               const float* __restrict__ b1,
                                               const float* __restrict__ W,
                                               const float* __restrict__ att_s,
                                               const float* __restrict__ att_d,
                                               float* __restrict__ hs,
                                               float* __restrict__ asrc,
                                               float* __restrict__ adst, int N) {
    __shared__ float Ws[32 * 128];
    __shared__ float trow[2][32];
    __shared__ float reds[4], redd[4];
    int tid = threadIdx.x;
    for (int i = tid; i < 4096; i += 256) Ws[i] = W[i];
    int n0 = blockIdx.x * 2;
    if (tid < 64) {
        int nl = tid >> 5, k = tid & 31;
        int g = n0 + nl;
        float v = (g < N) ? out1[(size_t)g * 32 + k] + b1[k] : 0.f;
        trow[nl][k] = fmaxf(v, 0.f);
    }
    __syncthreads();
    int nl = tid >> 7, j = tid & 127;
    int node = n0 + nl;
    float acc = 0.f;
#pragma unroll
    for (int k = 0; k < 32; ++k) acc += trow[nl][k] * Ws[k * 128 + j];
    float as = acc * att_s[j], ad = acc * att_d[j];
#pragma unroll
    for (int off = 32; off >= 1; off >>= 1) {
        as += __shfl_xor(as, off);
        ad += __shfl_xor(ad, off);
    }
    int w = tid >> 6;
    if ((tid & 63) == 0) { reds[w] = as; redd[w] = ad; }
    __syncthreads();
    if (node < N) {
        hs[(size_t)node * 128 + j] = acc;
        if (j == 0) {
            asrc[node] = reds[nl * 2] + reds[nl * 2 + 1];
            adst[node] = redd[nl * 2] + redd[nl * 2 + 1];
        }
    }
}

// -------- K7: layer-2 softmax + aggregation (C=128, 64 lanes/node) + b2 --------
__global__ __launch_bounds__(256) void k_agg2(const int* __restrict__ ro,
                                              const int* __restrict__ srcs,
                                              const float* __restrict__ ae2s,
                                              const float* __restrict__ asrc,
                                              const float* __restrict__ adst,
                                              const float* __restrict__ hs,
                                              const float* __restrict__ b2,
                                              float* __restrict__ out, int N) {
    int tid = threadIdx.x;
    int node = blockIdx.x * 4 + (tid >> 6);
    int gl = tid & 63;
    if (node >= N) return;
    int base = ro[node], end = ro[node + 1];
    float ad = adst[node];
    float m = -3.4e38f;
    for (int p = base + gl; p < end; p += 64) {
        int s = srcs[p];
        float al = asrc[s] + ad + ae2s[p];
        al = (al >= 0.f) ? al : NEG * al;
        m = fmaxf(m, al);
    }
#pragma unroll
    for (int off = 32; off >= 1; off >>= 1) m = fmaxf(m, __shfl_xor(m, off));
    float acc0 = 0.f, acc1 = 0.f, ss = 0.f;
    const float2* hp = (const float2*)hs;
    for (int p = base; p < end; ++p) {
        int s = srcs[p];
        float al = asrc[s] + ad + ae2s[p];
        al = (al >= 0.f) ? al : NEG * al;
        float w = __expf(al - m);
        ss += w;
        float2 hv = hp[(size_t)s * 64 + gl];
        acc0 += w * hv.x;
        acc1 += w * hv.y;
    }
    float inv = 1.f / (ss + 1e-16f);
    out[(size_t)node * 128 + gl * 2] = acc0 * inv + b2[gl * 2];
    out[(size_t)node * 128 + gl * 2 + 1] = acc1 * inv + b2[gl * 2 + 1];
}

extern "C" void kernel_launch(void* const* d_in, const int* in_sizes, int n_in,
                              void* d_out, int out_size, void* d_ws, size_t ws_size,
                              hipStream_t stream) {
    const void*  xRaw      = d_in[0];
    const void*  eiRaw     = d_in[1];
    const float* edge_attr = (const float*)d_in[2];
    const float* emb  = (const float*)d_in[3];
    const float* W1   = (const float*)d_in[4];
    const float* We1  = (const float*)d_in[5];
    const float* as1  = (const float*)d_in[6];
    const float* ad1v = (const float*)d_in[7];
    const float* ae1v = (const float*)d_in[8];
    const float* b1   = (const float*)d_in[9];
    const float* W2   = (const float*)d_in[10];
    const float* We2  = (const float*)d_in[11];
    const float* as2  = (const float*)d_in[12];
    const float* ad2v = (const float*)d_in[13];
    const float* ae2v = (const float*)d_in[14];
    const float* b2   = (const float*)d_in[15];
    float* out = (float*)d_out;

    int N = in_sizes[0];
    int E = in_sizes[1] / 2;

    // workspace carve-out (256B-aligned slices); total ≈ 54 MB
    char* w = (char*)d_ws;
    auto alloc = [&](size_t bytes) -> void* {
        void* p = (void*)w;
        w += (bytes + 255) & ~(size_t)255;
        return p;
    };
    float* v1     = (float*)alloc(384 * 4);
    float* v2     = (float*)alloc(384 * 4);
    float* aedge1 = (float*)alloc((size_t)E * 4);
    float* aedge2 = (float*)alloc((size_t)E * 4);
    float* hs1    = (float*)alloc((size_t)N * 32 * 4);
    float* a_src1 = (float*)alloc((size_t)N * 4);
    float* a_dst1 = (float*)alloc((size_t)N * 4);
    float* out1   = (float*)alloc((size_t)N * 32 * 4);
    float* hs2v   = (float*)alloc((size_t)N * 128 * 4);
    float* a_src2 = (float*)alloc((size_t)N * 4);
    float* a_dst2 = (float*)alloc((size_t)N * 4);
    int*   cnt    = (int*)alloc((size_t)(N + 1) * 4);
    int*   ro     = (int*)alloc((size_t)(N + 1) * 4);
    int*   cur    = (int*)alloc((size_t)(N + 1) * 4);
    int*   csum   = (int*)alloc(256 * 4);
    int*   srcs   = (int*)alloc((size_t)E * 4);
    float* ae1s   = (float*)alloc((size_t)E * 4);
    float* ae2s   = (float*)alloc((size_t)E * 4);
    int*   flag   = (int*)alloc(256);
    int*   xi     = (int*)alloc((size_t)N * 4);
    int*   eic    = (int*)alloc((size_t)2 * E * 4);  // [src | dst] int32-normalized
    const int* srcA = eic;
    const int* dstA = eic + E;

    hipMemsetAsync(cnt, 0, (size_t)N * 4, stream);

    // normalize index dtype (int64 or int32) into int32 ws buffers
    k_detect<<<1, 64, 0, stream>>>((const int*)eiRaw, flag);
    k_cvt<<<(N + 255) / 256, 256, 0, stream>>>(xRaw, xi, N, flag);
    k_cvt<<<(2 * E + 255) / 256, 256, 0, stream>>>(eiRaw, eic, 2 * E, flag);

    k_vedge<<<1, 384, 0, stream>>>(We1, ae1v, We2, ae2v, v1, v2);
    k_aedge<<<(E + 7) / 8, 256, 0, stream>>>(edge_attr, v1, v2, aedge1, aedge2, E);
    k_node1<<<(N + 7) / 8, 256, 0, stream>>>(xi, emb, W1, as1, ad1v, hs1, a_src1, a_dst1, N);
    k_count<<<(E + 255) / 256, 256, 0, stream>>>(dstA, cnt, E);
    int nch = (N + 255) / 256;
    k_scan1<<<nch, 256, 0, stream>>>(cnt, ro, csum, N);
    k_scan2<<<1, 256, 0, stream>>>(csum, nch);
    k_scan3<<<nch, 256, 0, stream>>>(ro, cur, csum, N);
    k_fill<<<(E + 255) / 256, 256, 0, stream>>>(srcA, dstA, aedge1, aedge2, cur, srcs, ae1s, ae2s, E);
    k_agg1<<<(N + 15) / 16, 256, 0, stream>>>(ro, srcs, ae1s, a_src1, a_dst1, hs1, out1, N);
    k_node2<<<(N + 1) / 2, 256, 0, stream>>>(out1, b1, W2, as2, ad2v, hs2v, a_src2, a_dst2, N);
    k_agg2<<<(N + 3) / 4, 256, 0, stream>>>(ro, srcs, ae2s, a_src2, a_dst2, hs2v, b2, out, N);
}

// Round 9
// 1218.405 us; speedup vs baseline: 1.0398x; 1.0398x over previous
//
#include <hip/hip_runtime.h>
#include <math.h>

#define NEG 0.2f

// -------- K_pre: (a) detect int64-vs-int32 index buffers via wave ballot,
//                 (b) v1 = We1 @ att_edge1 [384], v2 = We2 @ att_edge2 [384]
__global__ __launch_bounds__(384) void k_pre(const void* __restrict__ ei,
                                             const float* __restrict__ We1, const float* __restrict__ ae1,
                                             const float* __restrict__ We2, const float* __restrict__ ae2,
                                             float* __restrict__ v1, float* __restrict__ v2,
                                             int* __restrict__ flag) {
    int t = threadIdx.x;
    if (t < 64) {
        // as int32, an int64 array of values <2^31 has all odd words zero
        int vodd = ((const int*)ei)[2 * t + 1];
        unsigned long long nz = __ballot(vodd != 0);
        if (t == 0) *flag = (nz == 0ull) ? 1 : 0;  // 1 => int64
    }
    if (t < 384) {
        float a = 0.f;
        for (int j = 0; j < 32; ++j) a += We1[t * 32 + j] * ae1[j];
        v1[t] = a;
        float b = 0.f;
        for (int j = 0; j < 128; ++j) b += We2[t * 128 + j] * ae2[j];
        v2[t] = b;
    }
}

// -------- K1: a_edge{1,2}[e] = dot(edge_attr[e,:], v{1,2}) + fused dst-degree count
__global__ __launch_bounds__(256) void k_aedge(const float* __restrict__ ea,
                                               const void* __restrict__ ei,
                                               const float* __restrict__ v1,
                                               const float* __restrict__ v2,
                                               float* __restrict__ o1,
                                               float* __restrict__ o2,
                                               int* __restrict__ cnt,
                                               const int* __restrict__ flag, int E) {
    __shared__ float4 v1s[96], v2s[96];
    int tid = threadIdx.x;
    if (tid < 96) {
        v1s[tid] = ((const float4*)v1)[tid];
        v2s[tid] = ((const float4*)v2)[tid];
    }
    __syncthreads();
    int e = blockIdx.x * 8 + (tid >> 5);
    int gl = tid & 31;
    if (e >= E) return;
    const float4* p = (const float4*)ea + (size_t)e * 96;
    float a1 = 0.f, a2 = 0.f;
#pragma unroll
    for (int j = 0; j < 3; ++j) {
        int idx = j * 32 + gl;
        float4 x = p[idx];
        float4 w = v1s[idx];
        a1 += x.x * w.x + x.y * w.y + x.z * w.z + x.w * w.w;
        w = v2s[idx];
        a2 += x.x * w.x + x.y * w.y + x.z * w.z + x.w * w.w;
    }
#pragma unroll
    for (int off = 16; off >= 1; off >>= 1) {
        a1 += __shfl_xor(a1, off);
        a2 += __shfl_xor(a2, off);
    }
    if (gl == 0) {
        o1[e] = a1;
        o2[e] = a2;
        int d = (*flag) ? (int)((const long long*)ei)[E + e] : ((const int*)ei)[E + e];
        atomicAdd(&cnt[d], 1);
    }
}

// -------- K2: hs1 = emb[x] @ W1 [N,32]; a_src1, a_dst1 --------
__global__ __launch_bounds__(256) void k_node1(const void* __restrict__ x,
                                               const float* __restrict__ emb,
                                               const float* __restrict__ W,
                                               const float* __restrict__ att_s,
                                               const float* __restrict__ att_d,
                                               float* __restrict__ hs,
                                               float* __restrict__ asrc,
                                               float* __restrict__ adst,
                                               const int* __restrict__ flag, int N) {
    __shared__ float Ws[128 * 32];
    __shared__ float hrow[8][128];
    int tid = threadIdx.x;
    int fl = *flag;
    for (int i = tid; i < 4096; i += 256) Ws[i] = W[i];
    int n0 = blockIdx.x * 8;
    for (int i = tid; i < 8 * 128; i += 256) {
        int nl = i >> 7, k = i & 127;
        int g = n0 + nl;
        float v = 0.f;
        if (g < N) {
            long long xg = fl ? ((const long long*)x)[g] : (long long)((const int*)x)[g];
            v = emb[(size_t)xg * 128 + k];
        }
        hrow[nl][k] = v;
    }
    __syncthreads();
    int nl = tid >> 5, j = tid & 31;
    int node = n0 + nl;
    if (node >= N) return;
    float acc = 0.f;
#pragma unroll 8
    for (int k = 0; k < 128; ++k) acc += hrow[nl][k] * Ws[k * 32 + j];
    hs[(size_t)node * 32 + j] = acc;
    float as = acc * att_s[j], ad = acc * att_d[j];
#pragma unroll
    for (int off = 16; off >= 1; off >>= 1) {
        as += __shfl_xor(as, off);
        ad += __shfl_xor(ad, off);
    }
    if (j == 0) { asrc[node] = as; adst[node] = ad; }
}

// -------- CSR scan chain --------
__global__ void k_scan1(const int* __restrict__ cnt, int* __restrict__ ro,
                        int* __restrict__ csum, int N) {
    __shared__ int s[256];
    int t = threadIdx.x;
    int i = blockIdx.x * 256 + t;
    int v = (i < N) ? cnt[i] : 0;
    s[t] = v;
    __syncthreads();
    for (int off = 1; off < 256; off <<= 1) {
        int xv = (t >= off) ? s[t - off] : 0;
        __syncthreads();
        s[t] += xv;
        __syncthreads();
    }
    if (i < N) ro[i + 1] = s[t];
    if (t == 255) csum[blockIdx.x] = s[255];
}

__global__ void k_scan2(int* __restrict__ csum, int nch) {
    __shared__ int s[256];
    int t = threadIdx.x;
    int v = (t < nch) ? csum[t] : 0;
    s[t] = v;
    __syncthreads();
    for (int off = 1; off < 256; off <<= 1) {
        int xv = (t >= off) ? s[t - off] : 0;
        __syncthreads();
        s[t] += xv;
        __syncthreads();
    }
    if (t < nch) csum[t] = s[t] - v;  // exclusive chunk offsets
}

__global__ void k_scan3(int* __restrict__ ro, int* __restrict__ cur,
                        const int* __restrict__ csum, int N) {
    int i = blockIdx.x * 256 + threadIdx.x;
    if (i == 0) { ro[0] = 0; cur[0] = 0; }
    if (i < N) {
        int v = ro[i + 1] + csum[i >> 8];
        ro[i + 1] = v;
        cur[i + 1] = v;
    }
}

// -------- K4: fill packed payload {src, c1 = a_src1[src]+a_edge1, a_edge2} sorted by dst
__global__ void k_fill(const void* __restrict__ ei,
                       const float* __restrict__ ae1, const float* __restrict__ ae2,
                       const float* __restrict__ asrc1,
                       int* __restrict__ cur, int4* __restrict__ payload,
                       const int* __restrict__ flag, int E) {
    int e = blockIdx.x * 256 + threadIdx.x;
    if (e >= E) return;
    int fl = *flag;
    int s, d;
    if (fl) {
        s = (int)((const long long*)ei)[e];
        d = (int)((const long long*)ei)[E + e];
    } else {
        s = ((const int*)ei)[e];
        d = ((const int*)ei)[E + e];
    }
    int p = atomicAdd(&cur[d], 1);
    float c1 = asrc1[s] + ae1[e];
    payload[p] = make_int4(s, __float_as_int(c1), __float_as_int(ae2[e]), 0);
}

// -------- K5: layer-1 softmax + aggregation (C=32, 16 lanes/node, pipelined) --------
__global__ __launch_bounds__(256) void k_agg1(const int* __restrict__ ro,
                                              const int4* __restrict__ payload,
                                              const float* __restrict__ adst,
                                              const float* __restrict__ hs,
                                              float* __restrict__ out, int N) {
    int tid = threadIdx.x;
    int node = blockIdx.x * 16 + (tid >> 4);
    int gl = tid & 15;
    if (node >= N) return;
    int base = ro[node], end = ro[node + 1];
    float ad = adst[node];
    float m = -3.4e38f;
    for (int p = base + gl; p < end; p += 16) {
        float al = __int_as_float(payload[p].y) + ad;
        al = (al >= 0.f) ? al : NEG * al;
        m = fmaxf(m, al);
    }
#pragma unroll
    for (int off = 8; off >= 1; off >>= 1) m = fmaxf(m, __shfl_xor(m, off));
    const float2* hp = (const float2*)hs;
    int len = end - base;
    int4 pay0 = make_int4(0, 0, 0, 0), pay1 = make_int4(0, 0, 0, 0);
    float2 hv0 = make_float2(0.f, 0.f);
    if (len > 0) pay0 = payload[base];
    if (len > 1) pay1 = payload[base + 1];
    if (len > 0) hv0 = hp[(size_t)pay0.x * 16 + gl];
    float acc0 = 0.f, acc1 = 0.f, ss = 0.f;
    for (int i = 0; i < len; ++i) {
        int4 payc = pay0;
        float2 hvc = hv0;
        pay0 = pay1;
        if (i + 2 < len) pay1 = payload[base + i + 2];
        if (i + 1 < len) hv0 = hp[(size_t)pay0.x * 16 + gl];
        float al = __int_as_float(payc.y) + ad;
        al = (al >= 0.f) ? al : NEG * al;
        float w = __expf(al - m);
        ss += w;
        acc0 += w * hvc.x;
        acc1 += w * hvc.y;
    }
    float inv = 1.f / (ss + 1e-16f);
    out[(size_t)node * 32 + gl * 2] = acc0 * inv;
    out[(size_t)node * 32 + gl * 2 + 1] = acc1 * inv;
}

// -------- K6: t = relu(out1 + b1); hs2 = t @ W2 [N,128]; a_src2, a_dst2 --------
// 8 nodes per 1024-thread block (amortizes the 16 KB W2 load 4x better).
__global__ __launch_bounds__(1024) void k_node2(const float* __restrict__ out1,
                                                const float* __restrict__ b1,
                                                const float* __restrict__ W,
                                                const float* __restrict__ att_s,
                                                const float* __restrict__ att_d,
                                                float* __restrict__ hs,
                                                float* __restrict__ asrc,
                                                float* __restrict__ adst, int N) {
    __shared__ float Ws[32 * 128];
    __shared__ float trow[8][32];
    __shared__ float reds[16], redd[16];
    int tid = threadIdx.x;
    for (int i = tid; i < 4096; i += 1024) Ws[i] = W[i];
    int n0 = blockIdx.x * 8;
    if (tid < 256) {
        int nl = tid >> 5, k = tid & 31;
        int g = n0 + nl;
        float v = (g < N) ? out1[(size_t)g * 32 + k] + b1[k] : 0.f;
        trow[nl][k] = fmaxf(v, 0.f);
    }
    __syncthreads();
    int nl = tid >> 7, j = tid & 127;
    int node = n0 + nl;
    float acc = 0.f;
#pragma unroll
    for (int k = 0; k < 32; ++k) acc += trow[nl][k] * Ws[k * 128 + j];
    float as = acc * att_s[j], ad = acc * att_d[j];
#pragma unroll
    for (int off = 32; off >= 1; off >>= 1) {
        as += __shfl_xor(as, off);
        ad += __shfl_xor(ad, off);
    }
    int wv = tid >> 6;  // wave id 0..15; node nl spans waves 2nl, 2nl+1
    if ((tid & 63) == 0) { reds[wv] = as; redd[wv] = ad; }
    __syncthreads();
    if (node < N) {
        hs[(size_t)node * 128 + j] = acc;
        if (j == 0) {
            asrc[node] = reds[nl * 2] + reds[nl * 2 + 1];
            adst[node] = redd[nl * 2] + redd[nl * 2 + 1];
        }
    }
}

// -------- K7: layer-2 softmax + aggregation (C=128, 64 lanes/node, pipelined) + b2
__global__ __launch_bounds__(256) void k_agg2(const int* __restrict__ ro,
                                              const int4* __restrict__ payload,
                                              const float* __restrict__ asrc,
                                              const float* __restrict__ adst,
                                              const float* __restrict__ hs,
                                              const float* __restrict__ b2,
                                              float* __restrict__ out, int N) {
    int tid = threadIdx.x;
    int node = blockIdx.x * 4 + (tid >> 6);
    int gl = tid & 63;
    if (node >= N) return;
    int base = ro[node], end = ro[node + 1];
    float ad = adst[node];
    float m = -3.4e38f;
    for (int p = base + gl; p < end; p += 64) {
        int4 pay = payload[p];
        float al = asrc[pay.x] + ad + __int_as_float(pay.z);
        al = (al >= 0.f) ? al : NEG * al;
        m = fmaxf(m, al);
    }
#pragma unroll
    for (int off = 32; off >= 1; off >>= 1) m = fmaxf(m, __shfl_xor(m, off));
    const float2* hp = (const float2*)hs;
    int len = end - base;
    int4 pay0 = make_int4(0, 0, 0, 0), pay1 = make_int4(0, 0, 0, 0);
    float2 hv0 = make_float2(0.f, 0.f);
    float as0 = 0.f;
    if (len > 0) pay0 = payload[base];
    if (len > 1) pay1 = payload[base + 1];
    if (len > 0) { as0 = asrc[pay0.x]; hv0 = hp[(size_t)pay0.x * 64 + gl]; }
    float acc0 = 0.f, acc1 = 0.f, ss = 0.f;
    for (int i = 0; i < len; ++i) {
        int4 payc = pay0;
        float2 hvc = hv0;
        float asc = as0;
        pay0 = pay1;
        if (i + 2 < len) pay1 = payload[base + i + 2];
        if (i + 1 < len) { as0 = asrc[pay0.x]; hv0 = hp[(size_t)pay0.x * 64 + gl]; }
        float al = asc + ad + __int_as_float(payc.z);
        al = (al >= 0.f) ? al : NEG * al;
        float w = __expf(al - m);
        ss += w;
        acc0 += w * hvc.x;
        acc1 += w * hvc.y;
    }
    float inv = 1.f / (ss + 1e-16f);
    out[(size_t)node * 128 + gl * 2] = acc0 * inv + b2[gl * 2];
    out[(size_t)node * 128 + gl * 2 + 1] = acc1 * inv + b2[gl * 2 + 1];
}

extern "C" void kernel_launch(void* const* d_in, const int* in_sizes, int n_in,
                              void* d_out, int out_size, void* d_ws, size_t ws_size,
                              hipStream_t stream) {
    const void*  xRaw      = d_in[0];
    const void*  eiRaw     = d_in[1];
    const float* edge_attr = (const float*)d_in[2];
    const float* emb  = (const float*)d_in[3];
    const float* W1   = (const float*)d_in[4];
    const float* We1  = (const float*)d_in[5];
    const float* as1  = (const float*)d_in[6];
    const float* ad1v = (const float*)d_in[7];
    const float* ae1v = (const float*)d_in[8];
    const float* b1   = (const float*)d_in[9];
    const float* W2   = (const float*)d_in[10];
    const float* We2  = (const float*)d_in[11];
    const float* as2  = (const float*)d_in[12];
    const float* ad2v = (const float*)d_in[13];
    const float* ae2v = (const float*)d_in[14];
    const float* b2   = (const float*)d_in[15];
    float* out = (float*)d_out;

    int N = in_sizes[0];
    int E = in_sizes[1] / 2;

    // workspace carve-out (256B-aligned slices); total ~= 50 MB
    char* w = (char*)d_ws;
    auto alloc = [&](size_t bytes) -> void* {
        void* p = (void*)w;
        w += (bytes + 255) & ~(size_t)255;
        return p;
    };
    float* v1      = (float*)alloc(384 * 4);
    float* v2      = (float*)alloc(384 * 4);
    float* aedge1  = (float*)alloc((size_t)E * 4);
    float* aedge2  = (float*)alloc((size_t)E * 4);
    float* hs1     = (float*)alloc((size_t)N * 32 * 4);
    float* a_src1  = (float*)alloc((size_t)N * 4);
    float* a_dst1  = (float*)alloc((size_t)N * 4);
    float* out1    = (float*)alloc((size_t)N * 32 * 4);
    float* hs2v    = (float*)alloc((size_t)N * 128 * 4);
    float* a_src2  = (float*)alloc((size_t)N * 4);
    float* a_dst2  = (float*)alloc((size_t)N * 4);
    int*   cnt     = (int*)alloc((size_t)(N + 1) * 4);
    int*   ro      = (int*)alloc((size_t)(N + 1) * 4);
    int*   cur     = (int*)alloc((size_t)(N + 1) * 4);
    int*   csum    = (int*)alloc(256 * 4);
    int4*  payload = (int4*)alloc((size_t)E * 16);
    int*   flag    = (int*)alloc(256);

    hipMemsetAsync(cnt, 0, (size_t)N * 4, stream);

    k_pre<<<1, 384, 0, stream>>>(eiRaw, We1, ae1v, We2, ae2v, v1, v2, flag);
    k_aedge<<<(E + 7) / 8, 256, 0, stream>>>(edge_attr, eiRaw, v1, v2, aedge1, aedge2, cnt, flag, E);
    k_node1<<<(N + 7) / 8, 256, 0, stream>>>(xRaw, emb, W1, as1, ad1v, hs1, a_src1, a_dst1, flag, N);
    int nch = (N + 255) / 256;
    k_scan1<<<nch, 256, 0, stream>>>(cnt, ro, csum, N);
    k_scan2<<<1, 256, 0, stream>>>(csum, nch);
    k_scan3<<<nch, 256, 0, stream>>>(ro, cur, csum, N);
    k_fill<<<(E + 255) / 256, 256, 0, stream>>>(eiRaw, aedge1, aedge2, a_src1, cur, payload, flag, E);
    k_agg1<<<(N + 15) / 16, 256, 0, stream>>>(ro, payload, a_dst1, hs1, out1, N);
    k_node2<<<(N + 7) / 8, 1024, 0, stream>>>(out1, b1, W2, as2, ad2v, hs2v, a_src2, a_dst2, N);
    k_agg2<<<(N + 3) / 4, 256, 0, stream>>>(ro, payload, a_src2, a_dst2, hs2v, b2, out, N);
}